// Round 1
// baseline (3184.746 us; speedup 1.0000x reference)
//
#include <hip/hip_runtime.h>

#define NN 8192
#define SS 64
#define BB 8
#define BSD 512                 // B*S
#define NS (NN*SS)              // 524288
#define NBS (NN*BSD)            // 4194304

// ---------------------------------------------------------------- gate
__global__ void sigmoid_gate_kernel(const float* __restrict__ ent, float* __restrict__ gate) {
    int i = blockIdx.x * 256 + threadIdx.x;
    gate[i] = 1.0f / (1.0f + expf(-ent[i]));
}

// ------------------------------------------------- transpose + gate x0
// Y[n*512 + b*64 + s] = x[b][n][s] * gate[n][s]
__global__ void prep_kernel(const float* __restrict__ x, const float* __restrict__ gate,
                            float* __restrict__ Y) {
    int idx = blockIdx.x * 256 + threadIdx.x;       // n*512 + b*64 + s
    int n = idx >> 9;
    int b = (idx >> 6) & 7;
    int s = idx & 63;
    Y[idx] = x[((size_t)b * NN + n) * SS + s] * gate[(n << 6) + s];
}

// ---------------------------------------------------------------- GEMM
// X[m][bs] = sum_k Mix[k][m] * Yg[k][bs];  M=N=8192(K), C-tile 128x128, BK=16
__global__ __launch_bounds__(256) void gemm_kernel(const float* __restrict__ Mx,
                                                   const float* __restrict__ Yg,
                                                   float* __restrict__ X) {
    __shared__ __attribute__((aligned(16))) float As[2][16][132];  // Mix tile [k][m_local]
    __shared__ __attribute__((aligned(16))) float Bs[2][16][132];  // Yg  tile [k][bs_local]
    const int t  = threadIdx.x;
    const int tx = t & 15, ty = t >> 4;
    const int m0 = blockIdx.x * 128, bs0 = blockIdx.y * 128;

    // staging: 1024 float4 per tile (As 512 + Bs 512), 4 per thread
    const int e0 = t, e1 = t + 256;
    const int ka0 = e0 >> 5, ca0 = (e0 & 31) << 2;   // k 0..7
    const int ka1 = e1 >> 5, ca1 = (e1 & 31) << 2;   // k 8..15

    float acc[8][8];
    #pragma unroll
    for (int i = 0; i < 8; ++i)
        #pragma unroll
        for (int j = 0; j < 8; ++j) acc[i][j] = 0.0f;

    float4 ra0, ra1, rb0, rb1;
    // prologue: tile 0
    ra0 = *(const float4*)&Mx[(size_t)ka0 * NN + m0 + ca0];
    ra1 = *(const float4*)&Mx[(size_t)ka1 * NN + m0 + ca1];
    rb0 = *(const float4*)&Yg[(size_t)ka0 * BSD + bs0 + ca0];
    rb1 = *(const float4*)&Yg[(size_t)ka1 * BSD + bs0 + ca1];
    *(float4*)&As[0][ka0][ca0] = ra0;
    *(float4*)&As[0][ka1][ca1] = ra1;
    *(float4*)&Bs[0][ka0][ca0] = rb0;
    *(float4*)&Bs[0][ka1][ca1] = rb1;
    __syncthreads();

    const int nt = NN / 16;   // 512
    for (int kt = 0; kt < nt; ++kt) {
        const int cur = kt & 1, nxt = cur ^ 1;
        const bool pf = (kt + 1) < nt;
        if (pf) {
            const size_t k0 = (size_t)(kt + 1) * 16;
            ra0 = *(const float4*)&Mx[(k0 + ka0) * NN + m0 + ca0];
            ra1 = *(const float4*)&Mx[(k0 + ka1) * NN + m0 + ca1];
            rb0 = *(const float4*)&Yg[(k0 + ka0) * BSD + bs0 + ca0];
            rb1 = *(const float4*)&Yg[(k0 + ka1) * BSD + bs0 + ca1];
        }
        #pragma unroll
        for (int k = 0; k < 16; ++k) {
            float a[8], b[8];
            *(float4*)&a[0] = *(const float4*)&As[cur][k][ty * 4];
            *(float4*)&a[4] = *(const float4*)&As[cur][k][64 + ty * 4];
            *(float4*)&b[0] = *(const float4*)&Bs[cur][k][tx * 4];
            *(float4*)&b[4] = *(const float4*)&Bs[cur][k][64 + tx * 4];
            #pragma unroll
            for (int i = 0; i < 8; ++i)
                #pragma unroll
                for (int j = 0; j < 8; ++j)
                    acc[i][j] += a[i] * b[j];
        }
        if (pf) {
            *(float4*)&As[nxt][ka0][ca0] = ra0;
            *(float4*)&As[nxt][ka1][ca1] = ra1;
            *(float4*)&Bs[nxt][ka0][ca0] = rb0;
            *(float4*)&Bs[nxt][ka1][ca1] = rb1;
        }
        __syncthreads();
    }

    #pragma unroll
    for (int i = 0; i < 8; ++i) {
        const int row = m0 + ((i >> 2) << 6) + ty * 4 + (i & 3);
        float4 v0 = make_float4(acc[i][0], acc[i][1], acc[i][2], acc[i][3]);
        float4 v1 = make_float4(acc[i][4], acc[i][5], acc[i][6], acc[i][7]);
        *(float4*)&X[(size_t)row * BSD + bs0 + tx * 4] = v0;
        *(float4*)&X[(size_t)row * BSD + bs0 + 64 + tx * 4] = v1;
    }
}

// ------------------------------------------- mean over b (+ gate for next A)
__global__ void meangate_kernel(const float* __restrict__ X, const float* __restrict__ gate,
                                float* __restrict__ ns0, float* __restrict__ Yg) {
    int gtid = blockIdx.x * 256 + threadIdx.x;      // n*64 + s
    int n = gtid >> 6;
    int s = gtid & 63;
    const float* row = X + (size_t)n * BSD;
    float acc = 0.0f;
    if (Yg) {
        float g = gate[gtid];
        #pragma unroll
        for (int b = 0; b < 8; ++b) {
            float v = row[b * 64 + s];
            acc += v;
            Yg[(size_t)n * BSD + b * 64 + s] = v * g;
        }
    } else {
        #pragma unroll
        for (int b = 0; b < 8; ++b) acc += row[b * 64 + s];
    }
    ns0[gtid] = acc * 0.125f;
}

// ---------------------------------------------------------------- readout
// out[b][n][s] = sum_sp X3[n][b*64+sp] * W[s][sp]
__global__ __launch_bounds__(256) void readout_kernel(const float* __restrict__ X3,
                                                      const float* __restrict__ W,
                                                      float* __restrict__ out) {
    __shared__ float Wt[64][65];   // Wt[sp][s] = W[s][sp]
    __shared__ float xr[512];
    const int n = blockIdx.x;
    const int t = threadIdx.x;
    for (int e = t; e < 4096; e += 256) {
        int s = e >> 6, sp = e & 63;
        Wt[sp][s] = W[e];
    }
    xr[t]       = X3[(size_t)n * BSD + t];
    xr[t + 256] = X3[(size_t)n * BSD + 256 + t];
    __syncthreads();

    const int b1 = t >> 6;          // 0..3 (wave-uniform)
    const int s  = t & 63;
    float acc0 = 0.0f, acc1 = 0.0f;
    #pragma unroll
    for (int sp = 0; sp < 64; ++sp) {
        float w = Wt[sp][s];
        acc0 += w * xr[b1 * 64 + sp];
        acc1 += w * xr[(b1 + 4) * 64 + sp];
    }
    out[((size_t)b1 * NN + n) * SS + s]       = acc0;
    out[((size_t)(b1 + 4) * NN + n) * SS + s] = acc1;
}

// --------------------------------- temporal avg + enc + dec + top-k collapse
__global__ void nsfinal_kernel(const float* __restrict__ ns0,
                               const float* __restrict__ enc_w, const float* __restrict__ enc_b,
                               const float* __restrict__ dec_w, const float* __restrict__ dec_b,
                               float* __restrict__ out_ns) {
    int gtid = blockIdx.x * 256 + threadIdx.x;      // n*64 + s
    int lane = gtid & 63;
    const float r = 0.9f;
    const float wsum = 1.0f + r + r * r;
    float tns = (ns0[gtid] * (r * r) + ns0[NS + gtid] * r + ns0[2 * NS + gtid]) / wsum;

    float v = dec_b[lane];
    #pragma unroll
    for (int c = 0; c < 16; ++c) {
        float p = tns * enc_w[c * 64 + lane];
        #pragma unroll
        for (int off = 32; off; off >>= 1) p += __shfl_xor(p, off, 64);
        float h = fmaxf(p + enc_b[c], 0.0f);
        v += h * dec_w[lane * 16 + c];
    }
    // keep iff fewer than 8 strictly-greater |values| in the row  (== a >= thr_8)
    float av = fabsf(v);
    int cnt = 0;
    for (int j = 0; j < 64; ++j) {
        float o = __shfl(av, j, 64);
        cnt += (o > av) ? 1 : 0;
    }
    out_ns[gtid] = (cnt < 8) ? v : 0.0f;
}

// ---------------------------------------------------------------- launch
extern "C" void kernel_launch(void* const* d_in, const int* in_sizes, int n_in,
                              void* d_out, int out_size, void* d_ws, size_t ws_size,
                              hipStream_t stream) {
    const float* x      = (const float*)d_in[0];
    const float* ent    = (const float*)d_in[1];
    const float* mixing = (const float*)d_in[2];
    const float* r_w    = (const float*)d_in[3];
    const float* enc_w  = (const float*)d_in[4];
    const float* enc_b  = (const float*)d_in[5];
    const float* dec_w  = (const float*)d_in[6];
    const float* dec_b  = (const float*)d_in[7];
    float* out = (float*)d_out;

    float* gate = (float*)d_ws;          // NS
    float* Ya   = gate + NS;             // NBS  (gated K-major activation)
    float* Xb   = Ya + NBS;              // NBS  (GEMM output)
    float* ns0  = Xb + NBS;              // 3*NS (per-layer means)

    sigmoid_gate_kernel<<<NS / 256, 256, 0, stream>>>(ent, gate);
    prep_kernel<<<NBS / 256, 256, 0, stream>>>(x, gate, Ya);

    for (int l = 0; l < 3; ++l) {
        gemm_kernel<<<dim3(64, 4), 256, 0, stream>>>(mixing, Ya, Xb);
        meangate_kernel<<<2048, 256, 0, stream>>>(Xb, gate, ns0 + (size_t)l * NS,
                                                  (l < 2) ? Ya : nullptr);
    }

    readout_kernel<<<NN, 256, 0, stream>>>(Xb, r_w, out);
    nsfinal_kernel<<<2048, 256, 0, stream>>>(ns0, enc_w, enc_b, dec_w, dec_b, out + NBS);
}

// Round 3
// 901.804 us; speedup vs baseline: 3.5315x; 3.5315x over previous
//
#include <hip/hip_runtime.h>

#define NN 8192
#define SS 64
#define BSD 512                 // B*S
#define NS (NN*SS)              // 524288
#define NBS (NN*BSD)            // 4194304

typedef __attribute__((ext_vector_type(4))) _Float16 f16x4;
typedef __attribute__((ext_vector_type(8))) _Float16 f16x8;
typedef __attribute__((ext_vector_type(4))) float f32x4;

#define GLOAD_LDS16(gptr, lptr) \
    __builtin_amdgcn_global_load_lds((const __attribute__((address_space(1))) void*)(gptr), \
                                     (__attribute__((address_space(3))) void*)(lptr), 16, 0, 0)

// claimed (lane,elem)->k map inside a 32-k chunk; ONLY needs to be identical
// for A and B packs (self-canceling permutation in the MFMA dot product).
__device__ __forceinline__ int kmap(int lane, int e) {
    return ((lane >> 4) << 2) + (e & 3) + ((e >> 2) << 4);
}

// ---------------------------------------------------------------- gate
__global__ void sigmoid_gate_kernel(const float* __restrict__ ent, float* __restrict__ gate) {
    int i = blockIdx.x * 256 + threadIdx.x;
    gate[i] = 1.0f / (1.0f + expf(-ent[i]));
}

// ================================================================= pack epilogue (shared)
// Lh/Ll hold a [64 k][<=128 col] fp32-split tile; emit frag-lane-major:
// tile layout: hi 16KB [blk 8][kk 2][lane 64][8 f16], then lo 16KB same.
__device__ __forceinline__ void pack_tile(const _Float16 (*Lh)[136], const _Float16 (*Ll)[136],
                                          char* tile, int t) {
    #pragma unroll
    for (int j = 0; j < 4; ++j) {
        int idx  = j * 256 + t;            // 0..1023
        int blk  = idx >> 7;               // 16-col block
        int kk   = (idx >> 6) & 1;         // 32-k chunk
        int lane = idx & 63;
        int col  = blk * 16 + (lane & 15);
        int kb   = kk * 32;
        f16x8 hv, lv;
        #pragma unroll
        for (int e = 0; e < 8; ++e) {
            int k = kb + kmap(lane, e);
            hv[e] = Lh[k][col];
            lv[e] = Ll[k][col];
        }
        *(f16x8*)(tile + idx * 16)         = hv;
        *(f16x8*)(tile + 16384 + idx * 16) = lv;
    }
}

// ================================================================= convA
// Mix[k][m] fp32 -> Abuf tile(mt,kt) at (mt*128+kt)*32768 bytes (frag-lane-major)
__global__ __launch_bounds__(256) void convA_kernel(const float* __restrict__ Mx,
                                                    char* __restrict__ Ab) {
    __shared__ _Float16 Lh[64][136];
    __shared__ _Float16 Ll[64][136];
    const int t = threadIdx.x;
    const int kt = blockIdx.x, mt = blockIdx.y;
    const int k0 = kt * 64, m0 = mt * 128;
    #pragma unroll
    for (int i = 0; i < 8; ++i) {
        int e = i * 256 + t;
        int kr = e >> 5, m4 = (e & 31) << 2;
        float4 v = *(const float4*)&Mx[(size_t)(k0 + kr) * NN + m0 + m4];
        f16x4 h, l;
        h[0] = (_Float16)v.x; l[0] = (_Float16)(v.x - (float)h[0]);
        h[1] = (_Float16)v.y; l[1] = (_Float16)(v.y - (float)h[1]);
        h[2] = (_Float16)v.z; l[2] = (_Float16)(v.z - (float)h[2]);
        h[3] = (_Float16)v.w; l[3] = (_Float16)(v.w - (float)h[3]);
        *(f16x4*)&Lh[kr][m4] = h;
        *(f16x4*)&Ll[kr][m4] = l;
    }
    __syncthreads();
    pack_tile(Lh, Ll, Ab + ((size_t)(mt * 128 + kt) << 15), t);
}

// ================================================================= prepB
// x[b][n][s]*gate -> Bbuf tile(kt,nbt) at (kt*4+nbt)*32768
__global__ __launch_bounds__(256) void prepB_kernel(const float* __restrict__ x,
                                                    const float* __restrict__ gate,
                                                    char* __restrict__ Bb) {
    __shared__ _Float16 Lh[64][136];
    __shared__ _Float16 Ll[64][136];
    const int t = threadIdx.x;
    const int kt = blockIdx.x, nbt = blockIdx.y;
    const int n0 = kt * 64;
    #pragma unroll
    for (int i = 0; i < 8; ++i) {
        int e = i * 256 + t;
        int kr = e >> 5, bl = (e & 31) << 2;          // col within 128-block
        int b = (nbt << 1) + (bl >> 6), s = bl & 63;
        float4 v = *(const float4*)&x[((size_t)b * NN + n0 + kr) * 64 + s];
        float4 g = *(const float4*)&gate[(size_t)(n0 + kr) * 64 + s];
        v.x *= g.x; v.y *= g.y; v.z *= g.z; v.w *= g.w;
        f16x4 h, l;
        h[0] = (_Float16)v.x; l[0] = (_Float16)(v.x - (float)h[0]);
        h[1] = (_Float16)v.y; l[1] = (_Float16)(v.y - (float)h[1]);
        h[2] = (_Float16)v.z; l[2] = (_Float16)(v.z - (float)h[2]);
        h[3] = (_Float16)v.w; l[3] = (_Float16)(v.w - (float)h[3]);
        *(f16x4*)&Lh[kr][bl] = h;
        *(f16x4*)&Ll[kr][bl] = l;
    }
    __syncthreads();
    pack_tile(Lh, Ll, Bb + ((size_t)(kt * 4 + nbt) << 15), t);
}

// ================================================================= gateconvB
// X[n][bs] fp32 * gate -> Bbuf (same layout)
__global__ __launch_bounds__(256) void gateconvB_kernel(const float* __restrict__ X,
                                                        const float* __restrict__ gate,
                                                        char* __restrict__ Bb) {
    __shared__ _Float16 Lh[64][136];
    __shared__ _Float16 Ll[64][136];
    const int t = threadIdx.x;
    const int kt = blockIdx.x, nbt = blockIdx.y;
    const int n0 = kt * 64;
    #pragma unroll
    for (int i = 0; i < 8; ++i) {
        int e = i * 256 + t;
        int kr = e >> 5, c4 = (e & 31) << 2;
        float4 v = *(const float4*)&X[(size_t)(n0 + kr) * BSD + nbt * 128 + c4];
        float4 g = *(const float4*)&gate[(size_t)(n0 + kr) * 64 + (c4 & 63)];
        v.x *= g.x; v.y *= g.y; v.z *= g.z; v.w *= g.w;
        f16x4 h, l;
        h[0] = (_Float16)v.x; l[0] = (_Float16)(v.x - (float)h[0]);
        h[1] = (_Float16)v.y; l[1] = (_Float16)(v.y - (float)h[1]);
        h[2] = (_Float16)v.z; l[2] = (_Float16)(v.z - (float)h[2]);
        h[3] = (_Float16)v.w; l[3] = (_Float16)(v.w - (float)h[3]);
        *(f16x4*)&Lh[kr][c4] = h;
        *(f16x4*)&Ll[kr][c4] = l;
    }
    __syncthreads();
    pack_tile(Lh, Ll, Bb + ((size_t)(kt * 4 + nbt) << 15), t);
}

// ================================================================= GEMM (MFMA split-f16)
// X[m][bs] = sum_k Mix[k][m]*Yg[k][bs].  Block 128x128, BK=64, 8 waves (2x4),
// wave = 64x32.  C = Ah*Bh + Ah*Bl + Al*Bh (Al*Bl dropped, ~2^-22 rel).
__global__ __launch_bounds__(512) void gemm_f16_kernel(const char* __restrict__ Ab,
                                                       const char* __restrict__ Bb,
                                                       float* __restrict__ X) {
    __shared__ char lds[65536];   // A tile 32KB (hi|lo) | B tile 32KB (hi|lo)
    const int t = threadIdx.x;
    const int L = blockIdx.x;
    // XCD swizzle: the 4 nbt-blocks of one mt share an XCD (A panel L2 reuse)
    const int mt  = (L & 7) + ((L >> 5) << 3);   // 0..63
    const int nbt = (L >> 3) & 3;                // 0..3
    const int lane = t & 63, wid = t >> 6;       // 8 waves
    const int wr = wid >> 2, wc = wid & 3;       // wave grid 2x4 (64 rows x 32 cols)

    auto stage = [&](int kt) {
        const char* ga = Ab + (((size_t)mt * 128 + kt) << 15);
        const char* gb = Bb + (((size_t)kt * 4 + nbt) << 15);
        #pragma unroll
        for (int i = 0; i < 4; ++i)
            GLOAD_LDS16(ga + wid * 4096 + i * 1024 + lane * 16,
                        lds + wid * 4096 + i * 1024);
        #pragma unroll
        for (int i = 0; i < 4; ++i)
            GLOAD_LDS16(gb + wid * 4096 + i * 1024 + lane * 16,
                        lds + 32768 + wid * 4096 + i * 1024);
    };

    f32x4 acc[4][2];
    #pragma unroll
    for (int fi = 0; fi < 4; ++fi)
        #pragma unroll
        for (int fj = 0; fj < 2; ++fj)
            acc[fi][fj] = (f32x4){0.f, 0.f, 0.f, 0.f};

    const char* Abase = lds + (size_t)(wr * 4) * 2048 + lane * 16;
    const char* Bbase = lds + 32768 + (size_t)(wc * 2) * 2048 + lane * 16;

    stage(0);
    for (int kt = 0; kt < 128; ++kt) {
        __syncthreads();     // compiler drains vmcnt before s_barrier -> tile ready
        #pragma unroll
        for (int kk = 0; kk < 2; ++kk) {
            const int ko = kk * 1024;
            f16x8 bh0 = *(const f16x8*)(Bbase + ko);
            f16x8 bh1 = *(const f16x8*)(Bbase + 2048 + ko);
            f16x8 bl0 = *(const f16x8*)(Bbase + 16384 + ko);
            f16x8 bl1 = *(const f16x8*)(Bbase + 16384 + 2048 + ko);
            #pragma unroll
            for (int fi = 0; fi < 4; ++fi) {
                f16x8 ah = *(const f16x8*)(Abase + fi * 2048 + ko);
                f16x8 al = *(const f16x8*)(Abase + fi * 2048 + 16384 + ko);
                acc[fi][0] = __builtin_amdgcn_mfma_f32_16x16x32_f16(ah, bh0, acc[fi][0], 0, 0, 0);
                acc[fi][0] = __builtin_amdgcn_mfma_f32_16x16x32_f16(ah, bl0, acc[fi][0], 0, 0, 0);
                acc[fi][0] = __builtin_amdgcn_mfma_f32_16x16x32_f16(al, bh0, acc[fi][0], 0, 0, 0);
                acc[fi][1] = __builtin_amdgcn_mfma_f32_16x16x32_f16(ah, bh1, acc[fi][1], 0, 0, 0);
                acc[fi][1] = __builtin_amdgcn_mfma_f32_16x16x32_f16(ah, bl1, acc[fi][1], 0, 0, 0);
                acc[fi][1] = __builtin_amdgcn_mfma_f32_16x16x32_f16(al, bh1, acc[fi][1], 0, 0, 0);
            }
        }
        __syncthreads();     // all waves done reading before overwrite
        if (kt < 127) stage(kt + 1);
    }

    // D layout (m89-verified): col = lane&15, row = (lane>>4)*4 + reg
    const int row0 = mt * 128 + wr * 64 + ((lane >> 4) << 2);
    const int col0 = nbt * 128 + wc * 32 + (lane & 15);
    #pragma unroll
    for (int fi = 0; fi < 4; ++fi)
        #pragma unroll
        for (int fj = 0; fj < 2; ++fj)
            #pragma unroll
            for (int j = 0; j < 4; ++j)
                X[(size_t)(row0 + fi * 16 + j) * BSD + col0 + fj * 16] = acc[fi][fj][j];
}

// ================================================================= mean over b
__global__ void mean_kernel(const float* __restrict__ X, float* __restrict__ ns0) {
    int gtid = blockIdx.x * 256 + threadIdx.x;      // n*64 + s
    int n = gtid >> 6, s = gtid & 63;
    const float* row = X + (size_t)n * BSD;
    float acc = 0.0f;
    #pragma unroll
    for (int b = 0; b < 8; ++b) acc += row[b * 64 + s];
    ns0[gtid] = acc * 0.125f;
}

// ================================================================= readout
__global__ __launch_bounds__(256) void readout_kernel(const float* __restrict__ X3,
                                                      const float* __restrict__ W,
                                                      float* __restrict__ out) {
    __shared__ float Wt[64][65];
    __shared__ float xr[512];
    const int n = blockIdx.x;
    const int t = threadIdx.x;
    for (int e = t; e < 4096; e += 256) {
        int s = e >> 6, sp = e & 63;
        Wt[sp][s] = W[e];
    }
    xr[t]       = X3[(size_t)n * BSD + t];
    xr[t + 256] = X3[(size_t)n * BSD + 256 + t];
    __syncthreads();
    const int b1 = t >> 6;
    const int s  = t & 63;
    float acc0 = 0.0f, acc1 = 0.0f;
    #pragma unroll
    for (int sp = 0; sp < 64; ++sp) {
        float w = Wt[sp][s];
        acc0 += w * xr[b1 * 64 + sp];
        acc1 += w * xr[(b1 + 4) * 64 + sp];
    }
    out[((size_t)b1 * NN + n) * SS + s]       = acc0;
    out[((size_t)(b1 + 4) * NN + n) * SS + s] = acc1;
}

// ================================== temporal avg + enc + dec + top-k collapse
__global__ void nsfinal_kernel(const float* __restrict__ ns0,
                               const float* __restrict__ enc_w, const float* __restrict__ enc_b,
                               const float* __restrict__ dec_w, const float* __restrict__ dec_b,
                               float* __restrict__ out_ns) {
    int gtid = blockIdx.x * 256 + threadIdx.x;
    int lane = gtid & 63;
    const float r = 0.9f;
    const float wsum = 1.0f + r + r * r;
    float tns = (ns0[gtid] * (r * r) + ns0[NS + gtid] * r + ns0[2 * NS + gtid]) / wsum;
    float v = dec_b[lane];
    #pragma unroll
    for (int c = 0; c < 16; ++c) {
        float p = tns * enc_w[c * 64 + lane];
        #pragma unroll
        for (int off = 32; off; off >>= 1) p += __shfl_xor(p, off, 64);
        float h = fmaxf(p + enc_b[c], 0.0f);
        v += h * dec_w[lane * 16 + c];
    }
    float av = fabsf(v);
    int cnt = 0;
    for (int j = 0; j < 64; ++j) {
        float o = __shfl(av, j, 64);
        cnt += (o > av) ? 1 : 0;
    }
    out_ns[gtid] = (cnt < 8) ? v : 0.0f;
}

// ================================================================= launch
extern "C" void kernel_launch(void* const* d_in, const int* in_sizes, int n_in,
                              void* d_out, int out_size, void* d_ws, size_t ws_size,
                              hipStream_t stream) {
    const float* x      = (const float*)d_in[0];
    const float* ent    = (const float*)d_in[1];
    const float* mixing = (const float*)d_in[2];
    const float* r_w    = (const float*)d_in[3];
    const float* enc_w  = (const float*)d_in[4];
    const float* enc_b  = (const float*)d_in[5];
    const float* dec_w  = (const float*)d_in[6];
    const float* dec_b  = (const float*)d_in[7];
    float* out = (float*)d_out;

    const size_t ABYTES = 268435456ull;   // 8192 x (8192 k) x 2 (hi,lo) x 2B
    const size_t BBYTES = 16777216ull;    // 128*4 tiles x 32KB

    char*  Ab   = (char*)d_ws;
    char*  Bb   = Ab + ABYTES;
    float* Xb   = (float*)(Bb + BBYTES);
    float* ns0  = Xb + NBS;
    float* gate = ns0 + 3 * (size_t)NS;

    sigmoid_gate_kernel<<<NS / 256, 256, 0, stream>>>(ent, gate);
    convA_kernel<<<dim3(128, 64), 256, 0, stream>>>(mixing, Ab);
    prepB_kernel<<<dim3(128, 4), 256, 0, stream>>>(x, gate, Bb);

    for (int l = 0; l < 3; ++l) {
        gemm_f16_kernel<<<256, 512, 0, stream>>>(Ab, Bb, Xb);
        mean_kernel<<<2048, 256, 0, stream>>>(Xb, ns0 + (size_t)l * NS);
        if (l < 2)
            gateconvB_kernel<<<dim3(128, 4), 256, 0, stream>>>(Xb, gate, Bb);
    }

    readout_kernel<<<NN, 256, 0, stream>>>(Xb, r_w, out);
    nsfinal_kernel<<<2048, 256, 0, stream>>>(ns0, enc_w, enc_b, dec_w, dec_b, out + NBS);
}

// Round 5
// 848.929 us; speedup vs baseline: 3.7515x; 1.0623x over previous
//
#include <hip/hip_runtime.h>

#define NN 8192
#define SS 64
#define BSD 512                 // B*S
#define NS (NN*SS)              // 524288
#define NBS (NN*BSD)            // 4194304

typedef __attribute__((ext_vector_type(4))) _Float16 f16x4;
typedef __attribute__((ext_vector_type(8))) _Float16 f16x8;
typedef __attribute__((ext_vector_type(4))) float f32x4;

#define GLOAD_LDS16(gptr, lptr) \
    __builtin_amdgcn_global_load_lds((const __attribute__((address_space(1))) void*)(gptr), \
                                     (__attribute__((address_space(3))) void*)(lptr), 16, 0, 0)

// claimed (lane,elem)->k map inside a 32-k chunk; only needs to be identical
// for A and B packs (self-canceling bijection in the MFMA dot product).
// Empirically validated by round-3 pass with random asymmetric Mix.
__device__ __forceinline__ int kmap(int lane, int e) {
    return ((lane >> 4) << 2) + (e & 3) + ((e >> 2) << 4);
}

// ---------------------------------------------------------------- gate
__global__ void sigmoid_gate_kernel(const float* __restrict__ ent, float* __restrict__ gate) {
    int i = blockIdx.x * 256 + threadIdx.x;
    gate[i] = 1.0f / (1.0f + expf(-ent[i]));
}

// ================================================================= pack epilogue (shared)
// Lh/Ll hold a [64 k][<=128 col] fp32-split tile; emit frag-lane-major:
// tile layout: hi 16KB [blk 8][kk 2][lane 64][8 f16], then lo 16KB same.
__device__ __forceinline__ void pack_tile(const _Float16 (*Lh)[136], const _Float16 (*Ll)[136],
                                          char* tile, int t) {
    #pragma unroll
    for (int j = 0; j < 4; ++j) {
        int idx  = j * 256 + t;            // 0..1023
        int blk  = idx >> 7;               // 16-col block
        int kk   = (idx >> 6) & 1;         // 32-k chunk
        int lane = idx & 63;
        int col  = blk * 16 + (lane & 15);
        int kb   = kk * 32;
        f16x8 hv, lv;
        #pragma unroll
        for (int e = 0; e < 8; ++e) {
            int k = kb + kmap(lane, e);
            hv[e] = Lh[k][col];
            lv[e] = Ll[k][col];
        }
        *(f16x8*)(tile + idx * 16)         = hv;
        *(f16x8*)(tile + 16384 + idx * 16) = lv;
    }
}

// ================================================================= convA
// Mix[k][m] fp32 -> Abuf tile(mt,kt) at (mt*128+kt)*32768 bytes (frag-lane-major)
__global__ __launch_bounds__(256) void convA_kernel(const float* __restrict__ Mx,
                                                    char* __restrict__ Ab) {
    __shared__ _Float16 Lh[64][136];
    __shared__ _Float16 Ll[64][136];
    const int t = threadIdx.x;
    const int kt = blockIdx.x, mt = blockIdx.y;
    const int k0 = kt * 64, m0 = mt * 128;
    #pragma unroll
    for (int i = 0; i < 8; ++i) {
        int e = i * 256 + t;
        int kr = e >> 5, m4 = (e & 31) << 2;
        float4 v = *(const float4*)&Mx[(size_t)(k0 + kr) * NN + m0 + m4];
        f16x4 h, l;
        h[0] = (_Float16)v.x; l[0] = (_Float16)(v.x - (float)h[0]);
        h[1] = (_Float16)v.y; l[1] = (_Float16)(v.y - (float)h[1]);
        h[2] = (_Float16)v.z; l[2] = (_Float16)(v.z - (float)h[2]);
        h[3] = (_Float16)v.w; l[3] = (_Float16)(v.w - (float)h[3]);
        *(f16x4*)&Lh[kr][m4] = h;
        *(f16x4*)&Ll[kr][m4] = l;
    }
    __syncthreads();
    pack_tile(Lh, Ll, Ab + ((size_t)(mt * 128 + kt) << 15), t);
}

// ================================================================= prepB
// x[b][n][s]*gate -> Bbuf tile(kt,nbt) at (kt*4+nbt)*32768
__global__ __launch_bounds__(256) void prepB_kernel(const float* __restrict__ x,
                                                    const float* __restrict__ gate,
                                                    char* __restrict__ Bb) {
    __shared__ _Float16 Lh[64][136];
    __shared__ _Float16 Ll[64][136];
    const int t = threadIdx.x;
    const int kt = blockIdx.x, nbt = blockIdx.y;
    const int n0 = kt * 64;
    #pragma unroll
    for (int i = 0; i < 8; ++i) {
        int e = i * 256 + t;
        int kr = e >> 5, bl = (e & 31) << 2;          // col within 128-block
        int b = (nbt << 1) + (bl >> 6), s = bl & 63;
        float4 v = *(const float4*)&x[((size_t)b * NN + n0 + kr) * 64 + s];
        float4 g = *(const float4*)&gate[(size_t)(n0 + kr) * 64 + s];
        v.x *= g.x; v.y *= g.y; v.z *= g.z; v.w *= g.w;
        f16x4 h, l;
        h[0] = (_Float16)v.x; l[0] = (_Float16)(v.x - (float)h[0]);
        h[1] = (_Float16)v.y; l[1] = (_Float16)(v.y - (float)h[1]);
        h[2] = (_Float16)v.z; l[2] = (_Float16)(v.z - (float)h[2]);
        h[3] = (_Float16)v.w; l[3] = (_Float16)(v.w - (float)h[3]);
        *(f16x4*)&Lh[kr][bl] = h;
        *(f16x4*)&Ll[kr][bl] = l;
    }
    __syncthreads();
    pack_tile(Lh, Ll, Bb + ((size_t)(kt * 4 + nbt) << 15), t);
}

// ================================================================= gateconvB
// X[n][bs] fp32 * gate -> Bbuf (same layout)
__global__ __launch_bounds__(256) void gateconvB_kernel(const float* __restrict__ X,
                                                        const float* __restrict__ gate,
                                                        char* __restrict__ Bb) {
    __shared__ _Float16 Lh[64][136];
    __shared__ _Float16 Ll[64][136];
    const int t = threadIdx.x;
    const int kt = blockIdx.x, nbt = blockIdx.y;
    const int n0 = kt * 64;
    #pragma unroll
    for (int i = 0; i < 8; ++i) {
        int e = i * 256 + t;
        int kr = e >> 5, c4 = (e & 31) << 2;
        float4 v = *(const float4*)&X[(size_t)(n0 + kr) * BSD + nbt * 128 + c4];
        float4 g = *(const float4*)&gate[(size_t)(n0 + kr) * 64 + (c4 & 63)];
        v.x *= g.x; v.y *= g.y; v.z *= g.z; v.w *= g.w;
        f16x4 h, l;
        h[0] = (_Float16)v.x; l[0] = (_Float16)(v.x - (float)h[0]);
        h[1] = (_Float16)v.y; l[1] = (_Float16)(v.y - (float)h[1]);
        h[2] = (_Float16)v.z; l[2] = (_Float16)(v.z - (float)h[2]);
        h[3] = (_Float16)v.w; l[3] = (_Float16)(v.w - (float)h[3]);
        *(f16x4*)&Lh[kr][c4] = h;
        *(f16x4*)&Ll[kr][c4] = l;
    }
    __syncthreads();
    pack_tile(Lh, Ll, Bb + ((size_t)(kt * 4 + nbt) << 15), t);
}

// ================================================================= GEMM (MFMA split-f16)
// X[m][bs] = sum_k Mix[k][m]*Yg[k][bs].  Block 128x128, BK=64, 8 waves (2x4),
// wave = 64x32.  C = Ah*Bh + Ah*Bl + Al*Bh (Al*Bl dropped, ~2^-22 rel).
// Double-buffered LDS (2x64KB), prefetch-early + counted vmcnt (round-4 proven).
__global__ __launch_bounds__(512) void gemm_f16_kernel(const char* __restrict__ Ab,
                                                       const char* __restrict__ Bb,
                                                       float* __restrict__ X) {
    __shared__ char lds[2][65536];   // per buf: A hi|lo 32KB, B hi|lo 32KB
    const int t = threadIdx.x;
    const int L = blockIdx.x;
    // XCD swizzle: the 4 nbt-blocks of one mt share an XCD (A panel L2 reuse)
    const int mt  = (L & 7) + ((L >> 5) << 3);   // 0..63
    const int nbt = (L >> 3) & 3;                // 0..3
    const int lane = t & 63, wid = t >> 6;       // 8 waves
    const int wr = wid >> 2, wc = wid & 3;       // wave grid 2x4 (64 rows x 32 cols)

    auto stage = [&](int buf, int kt) {
        const char* ga = Ab + (((size_t)mt * 128 + kt) << 15);
        const char* gb = Bb + (((size_t)kt * 4 + nbt) << 15);
        char* la = lds[buf];
        #pragma unroll
        for (int i = 0; i < 4; ++i)
            GLOAD_LDS16(ga + wid * 4096 + i * 1024 + lane * 16,
                        la + wid * 4096 + i * 1024);
        #pragma unroll
        for (int i = 0; i < 4; ++i)
            GLOAD_LDS16(gb + wid * 4096 + i * 1024 + lane * 16,
                        la + 32768 + wid * 4096 + i * 1024);
    };   // 8 loads per lane per tile

    f32x4 acc[4][2];
    #pragma unroll
    for (int fi = 0; fi < 4; ++fi)
        #pragma unroll
        for (int fj = 0; fj < 2; ++fj)
            acc[fi][fj] = (f32x4){0.f, 0.f, 0.f, 0.f};

    stage(0, 0);
    for (int kt = 0; kt < 128; ++kt) {
        const int cur = kt & 1;
        if (kt < 127) {
            stage(cur ^ 1, kt + 1);                           // prefetch next tile
            asm volatile("s_waitcnt vmcnt(8)" ::: "memory");  // own cur-tile loads done
        } else {
            asm volatile("s_waitcnt vmcnt(0)" ::: "memory");
        }
        __builtin_amdgcn_s_barrier();                         // cur tile visible to all
        __builtin_amdgcn_sched_barrier(0);
        const char* base  = lds[cur];
        const char* Abase = base + wr * 8192 + lane * 16;            // +fi*2048, +16384 lo
        const char* Bbase = base + 32768 + wc * 4096 + lane * 16;    // +fj*2048, +16384 lo
        #pragma unroll
        for (int kk = 0; kk < 2; ++kk) {
            const int ko = kk * 1024;
            f16x8 bh0 = *(const f16x8*)(Bbase + ko);
            f16x8 bh1 = *(const f16x8*)(Bbase + 2048 + ko);
            f16x8 bl0 = *(const f16x8*)(Bbase + 16384 + ko);
            f16x8 bl1 = *(const f16x8*)(Bbase + 16384 + 2048 + ko);
            #pragma unroll
            for (int fi = 0; fi < 4; ++fi) {
                f16x8 ah = *(const f16x8*)(Abase + fi * 2048 + ko);
                f16x8 al = *(const f16x8*)(Abase + fi * 2048 + 16384 + ko);
                acc[fi][0] = __builtin_amdgcn_mfma_f32_16x16x32_f16(ah, bh0, acc[fi][0], 0, 0, 0);
                acc[fi][0] = __builtin_amdgcn_mfma_f32_16x16x32_f16(ah, bl0, acc[fi][0], 0, 0, 0);
                acc[fi][0] = __builtin_amdgcn_mfma_f32_16x16x32_f16(al, bh0, acc[fi][0], 0, 0, 0);
                acc[fi][1] = __builtin_amdgcn_mfma_f32_16x16x32_f16(ah, bh1, acc[fi][1], 0, 0, 0);
                acc[fi][1] = __builtin_amdgcn_mfma_f32_16x16x32_f16(ah, bl1, acc[fi][1], 0, 0, 0);
                acc[fi][1] = __builtin_amdgcn_mfma_f32_16x16x32_f16(al, bh1, acc[fi][1], 0, 0, 0);
            }
        }
        __builtin_amdgcn_sched_barrier(0);
        __builtin_amdgcn_s_barrier();                         // all reads of cur done
    }

    // D layout (m89-verified): col = lane&15, row = (lane>>4)*4 + reg
    const int row0 = mt * 128 + wr * 64 + ((lane >> 4) << 2);
    const int col0 = nbt * 128 + wc * 32 + (lane & 15);
    #pragma unroll
    for (int fi = 0; fi < 4; ++fi)
        #pragma unroll
        for (int fj = 0; fj < 2; ++fj)
            #pragma unroll
            for (int j = 0; j < 4; ++j)
                X[(size_t)(row0 + fi * 16 + j) * BSD + col0 + fj * 16] = acc[fi][fj][j];
}

// ================================================================= mean over b
__global__ void mean_kernel(const float* __restrict__ X, float* __restrict__ ns0) {
    int gtid = blockIdx.x * 256 + threadIdx.x;      // n*64 + s
    int n = gtid >> 6, s = gtid & 63;
    const float* row = X + (size_t)n * BSD;
    float acc = 0.0f;
    #pragma unroll
    for (int b = 0; b < 8; ++b) acc += row[b * 64 + s];
    ns0[gtid] = acc * 0.125f;
}

// ================================================================= readout
__global__ __launch_bounds__(256) void readout_kernel(const float* __restrict__ X3,
                                                      const float* __restrict__ W,
                                                      float* __restrict__ out) {
    __shared__ float Wt[64][65];
    __shared__ float xr[512];
    const int n = blockIdx.x;
    const int t = threadIdx.x;
    for (int e = t; e < 4096; e += 256) {
        int s = e >> 6, sp = e & 63;
        Wt[sp][s] = W[e];
    }
    xr[t]       = X3[(size_t)n * BSD + t];
    xr[t + 256] = X3[(size_t)n * BSD + 256 + t];
    __syncthreads();
    const int b1 = t >> 6;
    const int s  = t & 63;
    float acc0 = 0.0f, acc1 = 0.0f;
    #pragma unroll
    for (int sp = 0; sp < 64; ++sp) {
        float w = Wt[sp][s];
        acc0 += w * xr[b1 * 64 + sp];
        acc1 += w * xr[(b1 + 4) * 64 + sp];
    }
    out[((size_t)b1 * NN + n) * SS + s]       = acc0;
    out[((size_t)(b1 + 4) * NN + n) * SS + s] = acc1;
}

// ================================== temporal avg + enc + dec + top-k collapse
__global__ void nsfinal_kernel(const float* __restrict__ ns0,
                               const float* __restrict__ enc_w, const float* __restrict__ enc_b,
                               const float* __restrict__ dec_w, const float* __restrict__ dec_b,
                               float* __restrict__ out_ns) {
    int gtid = blockIdx.x * 256 + threadIdx.x;
    int lane = gtid & 63;
    const float r = 0.9f;
    const float wsum = 1.0f + r + r * r;
    float tns = (ns0[gtid] * (r * r) + ns0[NS + gtid] * r + ns0[2 * NS + gtid]) / wsum;
    float v = dec_b[lane];
    #pragma unroll
    for (int c = 0; c < 16; ++c) {
        float p = tns * enc_w[c * 64 + lane];
        #pragma unroll
        for (int off = 32; off; off >>= 1) p += __shfl_xor(p, off, 64);
        float h = fmaxf(p + enc_b[c], 0.0f);
        v += h * dec_w[lane * 16 + c];
    }
    float av = fabsf(v);
    int cnt = 0;
    for (int j = 0; j < 64; ++j) {
        float o = __shfl(av, j, 64);
        cnt += (o > av) ? 1 : 0;
    }
    out_ns[gtid] = (cnt < 8) ? v : 0.0f;
}

// ================================================================= launch
extern "C" void kernel_launch(void* const* d_in, const int* in_sizes, int n_in,
                              void* d_out, int out_size, void* d_ws, size_t ws_size,
                              hipStream_t stream) {
    const float* x      = (const float*)d_in[0];
    const float* ent    = (const float*)d_in[1];
    const float* mixing = (const float*)d_in[2];
    const float* r_w    = (const float*)d_in[3];
    const float* enc_w  = (const float*)d_in[4];
    const float* enc_b  = (const float*)d_in[5];
    const float* dec_w  = (const float*)d_in[6];
    const float* dec_b  = (const float*)d_in[7];
    float* out = (float*)d_out;

    const size_t ABYTES = 268435456ull;   // 8192 x (8192 k) x 2 (hi,lo) x 2B
    const size_t BBYTES = 16777216ull;    // 128*4 tiles x 32KB

    char*  Ab   = (char*)d_ws;
    char*  Bb   = Ab + ABYTES;
    float* Xb   = (float*)(Bb + BBYTES);
    float* ns0  = Xb + NBS;
    float* gate = ns0 + 3 * (size_t)NS;

    sigmoid_gate_kernel<<<NS / 256, 256, 0, stream>>>(ent, gate);
    convA_kernel<<<dim3(128, 64), 256, 0, stream>>>(mixing, Ab);
    prepB_kernel<<<dim3(128, 4), 256, 0, stream>>>(x, gate, Bb);

    for (int l = 0; l < 3; ++l) {
        gemm_f16_kernel<<<256, 512, 0, stream>>>(Ab, Bb, Xb);
        mean_kernel<<<2048, 256, 0, stream>>>(Xb, ns0 + (size_t)l * NS);
        if (l < 2)
            gateconvB_kernel<<<dim3(128, 4), 256, 0, stream>>>(Xb, gate, Bb);
    }

    readout_kernel<<<NN, 256, 0, stream>>>(Xb, r_w, out);
    nsfinal_kernel<<<2048, 256, 0, stream>>>(ns0, enc_w, enc_b, dec_w, dec_b, out + NBS);
}

// Round 6
// 669.389 us; speedup vs baseline: 4.7577x; 1.2682x over previous
//
#include <hip/hip_runtime.h>

#define NN 8192
#define SS 64
#define BSD 512                 // B*S
#define NS (NN*SS)              // 524288
#define NBS (NN*BSD)            // 4194304

typedef __attribute__((ext_vector_type(4))) _Float16 f16x4;
typedef __attribute__((ext_vector_type(8))) _Float16 f16x8;
typedef __attribute__((ext_vector_type(4))) float f32x4;

#define GLOAD_LDS16(gptr, lptr) \
    __builtin_amdgcn_global_load_lds((const __attribute__((address_space(1))) void*)(gptr), \
                                     (__attribute__((address_space(3))) void*)(lptr), 16, 0, 0)

// claimed (lane,elem)->k map inside a 32-k chunk; only needs to be identical
// for A and B packs (self-canceling bijection in the MFMA dot product).
// Empirically validated by round-3/5 passes with random asymmetric Mix.
__device__ __forceinline__ int kmap(int lane, int e) {
    return ((lane >> 4) << 2) + (e & 3) + ((e >> 2) << 4);
}

// ---------------------------------------------------------------- gate
__global__ void sigmoid_gate_kernel(const float* __restrict__ ent, float* __restrict__ gate) {
    int i = blockIdx.x * 256 + threadIdx.x;
    gate[i] = 1.0f / (1.0f + expf(-ent[i]));
}

// ---------------------------------------------------------------- pack (hi/lo, 128 cols)
// tile: hi 16KB [blk 8][kk 2][lane 64][8 f16], then lo 16KB same.
__device__ __forceinline__ void pack_tile(const _Float16 (*Lh)[136], const _Float16 (*Ll)[136],
                                          char* tile, int t) {
    #pragma unroll
    for (int j = 0; j < 4; ++j) {
        int idx  = j * 256 + t;            // 0..1023
        int blk  = idx >> 7;
        int kk   = (idx >> 6) & 1;
        int lane = idx & 63;
        int col  = blk * 16 + (lane & 15);
        int kb   = kk * 32;
        f16x8 hv, lv;
        #pragma unroll
        for (int e = 0; e < 8; ++e) {
            int k = kb + kmap(lane, e);
            hv[e] = Lh[k][col];
            lv[e] = Ll[k][col];
        }
        *(f16x8*)(tile + idx * 16)         = hv;
        *(f16x8*)(tile + 16384 + idx * 16) = lv;
    }
}

// ================================================================= convA
// D[k][m] = Mix[k][m] - (k==m), split hi/lo f16; tile(mt,kt) at (mt*128+kt)*32768
__global__ __launch_bounds__(256) void convA_kernel(const float* __restrict__ Mx,
                                                    char* __restrict__ Ab) {
    __shared__ _Float16 Lh[64][136];
    __shared__ _Float16 Ll[64][136];
    const int t = threadIdx.x;
    const int kt = blockIdx.x, mt = blockIdx.y;
    const int k0 = kt * 64, m0 = mt * 128;
    #pragma unroll
    for (int i = 0; i < 8; ++i) {
        int e = i * 256 + t;
        int kr = e >> 5, m4 = (e & 31) << 2;
        float4 v = *(const float4*)&Mx[(size_t)(k0 + kr) * NN + m0 + m4];
        int d = (k0 + kr) - (m0 + m4);     // subtract identity where k == m
        if (d == 0) v.x -= 1.0f;
        if (d == 1) v.y -= 1.0f;
        if (d == 2) v.z -= 1.0f;
        if (d == 3) v.w -= 1.0f;
        f16x4 h, l;
        h[0] = (_Float16)v.x; l[0] = (_Float16)(v.x - (float)h[0]);
        h[1] = (_Float16)v.y; l[1] = (_Float16)(v.y - (float)h[1]);
        h[2] = (_Float16)v.z; l[2] = (_Float16)(v.z - (float)h[2]);
        h[3] = (_Float16)v.w; l[3] = (_Float16)(v.w - (float)h[3]);
        *(f16x4*)&Lh[kr][m4] = h;
        *(f16x4*)&Ll[kr][m4] = l;
    }
    __syncthreads();
    pack_tile(Lh, Ll, Ab + ((size_t)(mt * 128 + kt) << 15), t);
}

// ---------------------------------------------------------------- shared B pack
// Lh: [64 k][512 col] f16 of gated activation; Nh/Nl: [64 k][64 s] split of m_g.
// Bmain tile (16KB) per nbt; Bns tile (4KB = hi 2K | lo 2K) per nbt.
__device__ __forceinline__ void pack_B(const _Float16 (*Lh)[520],
                                       const _Float16 (*Nh)[72], const _Float16 (*Nl)[72],
                                       char* Bb, char* Nb, int kt, int t) {
    #pragma unroll
    for (int j = 0; j < 16; ++j) {
        int idx = j * 256 + t;             // 0..4095
        int nbt = idx >> 10, w = idx & 1023;
        int blk = w >> 7, kk = (w >> 6) & 1, lane = w & 63;
        int col = nbt * 128 + blk * 16 + (lane & 15);
        int kb = kk * 32;
        f16x8 hv;
        #pragma unroll
        for (int e = 0; e < 8; ++e)
            hv[e] = Lh[kb + kmap(lane, e)][col];
        *(f16x8*)(Bb + (((size_t)kt * 4 + nbt) << 14) + w * 16) = hv;
    }
    #pragma unroll
    for (int j = 0; j < 4; ++j) {
        int idx = j * 256 + t;             // 0..1023
        int nbt = idx >> 8, r = idx & 255;
        int part = r >> 7, kk = (r >> 6) & 1, lane = r & 63;
        int s = nbt * 16 + (lane & 15);
        int kb = kk * 32;
        f16x8 v;
        #pragma unroll
        for (int e = 0; e < 8; ++e) {
            int k = kb + kmap(lane, e);
            v[e] = part ? Nl[k][s] : Nh[k][s];
        }
        *(f16x8*)(Nb + (((size_t)kt * 4 + nbt) << 12) + part * 2048 + kk * 1024 + lane * 16) = v;
    }
}

// ================================================================= prep0 (layer 1 B)
// x -> X = x*gate (fp32), Bmain f16, m = mean_b(x), mg32 = m*gate, Bns split
__global__ __launch_bounds__(256) void prep0_kernel(const float* __restrict__ x,
                                                    const float* __restrict__ gate,
                                                    float* __restrict__ X,
                                                    char* __restrict__ Bb,
                                                    char* __restrict__ Nb,
                                                    float* __restrict__ mg32) {
    __shared__ _Float16 Lh[64][520];
    __shared__ _Float16 Nh[64][72];
    __shared__ _Float16 Nl[64][72];
    const int t = threadIdx.x;
    const int kt = blockIdx.x;
    const int n0 = kt * 64;
    #pragma unroll
    for (int i = 0; i < 4; ++i) {
        int e = i * 256 + t;           // 0..1023
        int kr = e >> 4;               // 0..63
        int s4 = (e & 15) << 2;        // 0..60
        float4 g = *(const float4*)&gate[(size_t)(n0 + kr) * 64 + s4];
        float4 ms = make_float4(0.f, 0.f, 0.f, 0.f);
        #pragma unroll
        for (int b = 0; b < 8; ++b) {
            float4 v = *(const float4*)&x[((size_t)b * NN + n0 + kr) * 64 + s4];
            ms.x += v.x; ms.y += v.y; ms.z += v.z; ms.w += v.w;
            v.x *= g.x; v.y *= g.y; v.z *= g.z; v.w *= g.w;
            *(float4*)&X[(size_t)(n0 + kr) * BSD + b * 64 + s4] = v;
            f16x4 h;
            h[0] = (_Float16)v.x; h[1] = (_Float16)v.y;
            h[2] = (_Float16)v.z; h[3] = (_Float16)v.w;
            *(f16x4*)&Lh[kr][b * 64 + s4] = h;
        }
        float4 mg4;
        mg4.x = ms.x * 0.125f * g.x; mg4.y = ms.y * 0.125f * g.y;
        mg4.z = ms.z * 0.125f * g.z; mg4.w = ms.w * 0.125f * g.w;
        *(float4*)&mg32[(size_t)(n0 + kr) * 64 + s4] = mg4;
        f16x4 mh, ml;
        mh[0] = (_Float16)mg4.x; ml[0] = (_Float16)(mg4.x - (float)mh[0]);
        mh[1] = (_Float16)mg4.y; ml[1] = (_Float16)(mg4.y - (float)mh[1]);
        mh[2] = (_Float16)mg4.z; ml[2] = (_Float16)(mg4.z - (float)mh[2]);
        mh[3] = (_Float16)mg4.w; ml[3] = (_Float16)(mg4.w - (float)mh[3]);
        *(f16x4*)&Nh[kr][s4] = mh;
        *(f16x4*)&Nl[kr][s4] = ml;
    }
    __syncthreads();
    pack_B(Lh, Nh, Nl, Bb, Nb, kt, t);
}

// ================================================================= gateconv (layers 2,3 B)
// X *= gate (in place), Bmain f16; mg = nsprev*gate -> mg32, Bns split
__global__ __launch_bounds__(256) void gateconv_kernel(float* __restrict__ X,
                                                       const float* __restrict__ gate,
                                                       const float* __restrict__ nsprev,
                                                       char* __restrict__ Bb,
                                                       char* __restrict__ Nb,
                                                       float* __restrict__ mg32) {
    __shared__ _Float16 Lh[64][520];
    __shared__ _Float16 Nh[64][72];
    __shared__ _Float16 Nl[64][72];
    const int t = threadIdx.x;
    const int kt = blockIdx.x;
    const int n0 = kt * 64;
    #pragma unroll
    for (int i = 0; i < 32; ++i) {
        int e = i * 256 + t;           // 0..8191
        int kr = e >> 7;               // 0..63
        int c4 = (e & 127) << 2;       // 0..508
        float4 v = *(const float4*)&X[(size_t)(n0 + kr) * BSD + c4];
        float4 g = *(const float4*)&gate[(size_t)(n0 + kr) * 64 + (c4 & 63)];
        v.x *= g.x; v.y *= g.y; v.z *= g.z; v.w *= g.w;
        *(float4*)&X[(size_t)(n0 + kr) * BSD + c4] = v;
        f16x4 h;
        h[0] = (_Float16)v.x; h[1] = (_Float16)v.y;
        h[2] = (_Float16)v.z; h[3] = (_Float16)v.w;
        *(f16x4*)&Lh[kr][c4] = h;
    }
    #pragma unroll
    for (int i = 0; i < 4; ++i) {
        int e = i * 256 + t;
        int kr = e >> 4;
        int s4 = (e & 15) << 2;
        float4 p = *(const float4*)&nsprev[(size_t)(n0 + kr) * 64 + s4];
        float4 g = *(const float4*)&gate[(size_t)(n0 + kr) * 64 + s4];
        float4 mg4;
        mg4.x = p.x * g.x; mg4.y = p.y * g.y; mg4.z = p.z * g.z; mg4.w = p.w * g.w;
        *(float4*)&mg32[(size_t)(n0 + kr) * 64 + s4] = mg4;
        f16x4 mh, ml;
        mh[0] = (_Float16)mg4.x; ml[0] = (_Float16)(mg4.x - (float)mh[0]);
        mh[1] = (_Float16)mg4.y; ml[1] = (_Float16)(mg4.y - (float)mh[1]);
        mh[2] = (_Float16)mg4.z; ml[2] = (_Float16)(mg4.z - (float)mh[2]);
        mh[3] = (_Float16)mg4.w; ml[3] = (_Float16)(mg4.w - (float)mh[3]);
        *(f16x4*)&Nh[kr][s4] = mh;
        *(f16x4*)&Nl[kr][s4] = ml;
    }
    __syncthreads();
    pack_B(Lh, Nh, Nl, Bb, Nb, kt, t);
}

// ================================================================= GEMM
// Main: X[m][c] = X_gated[m][c] + sum_k Dh[k][m]*Yg_f16[k][c]   (in-place X)
// ns:   ns[m][s] = mg[m][s] + sum_k (Dh*mh + Dh*ml + Dl*mh)[m][s]
// Block 128x(128 main + 16 ns), BK=64, 8 waves (2x4), dbuf LDS, counted vmcnt.
__global__ __launch_bounds__(512) void gemm_f16_kernel(const char* __restrict__ Ab,
                                                       const char* __restrict__ Bb,
                                                       const char* __restrict__ Nb,
                                                       float* X,
                                                       const float* __restrict__ mg,
                                                       float* __restrict__ nsout) {
    __shared__ char lds[2][53248];   // Ahi 16K | Alo 16K | Bmain 16K | Bns 4K
    const int t = threadIdx.x;
    const int L = blockIdx.x;
    const int mt  = (L & 7) + ((L >> 5) << 3);   // 0..63 (XCD swizzle)
    const int nbt = (L >> 3) & 3;                // 0..3
    const int lane = t & 63, wid = t >> 6;       // 8 waves
    const int wr = wid >> 2, wc = wid & 3;       // wave grid 2x4
    const int fins = wid & 3;                    // wave's ns row-frag (= its own fi)

    auto stage = [&](int buf, int kt) {
        const char* ga = Ab + (((size_t)mt * 128 + kt) << 15);
        const char* gb = Bb + (((size_t)kt * 4 + nbt) << 14);
        const char* gn = Nb + (((size_t)kt * 4 + nbt) << 12);
        char* la = lds[buf];
        GLOAD_LDS16(ga + wid * 2048 + lane * 16,                 la + wid * 2048);
        GLOAD_LDS16(ga + wid * 2048 + 1024 + lane * 16,          la + wid * 2048 + 1024);
        GLOAD_LDS16(ga + 16384 + wid * 2048 + lane * 16,         la + 16384 + wid * 2048);
        GLOAD_LDS16(ga + 16384 + wid * 2048 + 1024 + lane * 16,  la + 16384 + wid * 2048 + 1024);
        GLOAD_LDS16(gb + wid * 2048 + lane * 16,                 la + 32768 + wid * 2048);
        GLOAD_LDS16(gb + wid * 2048 + 1024 + lane * 16,          la + 32768 + wid * 2048 + 1024);
        if (wid < 4)
            GLOAD_LDS16(gn + wid * 1024 + lane * 16,             la + 49152 + wid * 1024);
    };   // 7 loads for waves 0-3, 6 for waves 4-7

    f32x4 accm[4][2];
    #pragma unroll
    for (int fi = 0; fi < 4; ++fi) {
        accm[fi][0] = (f32x4){0.f, 0.f, 0.f, 0.f};
        accm[fi][1] = (f32x4){0.f, 0.f, 0.f, 0.f};
    }
    f32x4 accn = (f32x4){0.f, 0.f, 0.f, 0.f};

    stage(0, 0);
    for (int kt = 0; kt < 128; ++kt) {
        const int cur = kt & 1;
        if (kt < 127) {
            stage(cur ^ 1, kt + 1);                               // prefetch next tile
            if (wid < 4) asm volatile("s_waitcnt vmcnt(7)" ::: "memory");
            else         asm volatile("s_waitcnt vmcnt(6)" ::: "memory");
        } else {
            asm volatile("s_waitcnt vmcnt(0)" ::: "memory");
        }
        __builtin_amdgcn_s_barrier();
        __builtin_amdgcn_sched_barrier(0);
        const char* base = lds[cur];
        const char* A_ = base + wr * 8192 + lane * 16;           // +fi*2048 (+16384 lo)
        const char* Bm = base + 32768 + wc * 4096 + lane * 16;   // +fj*2048
        const char* Bn = base + 49152 + lane * 16;               // hi +0, lo +2048
        #pragma unroll
        for (int kk = 0; kk < 2; ++kk) {
            const int ko = kk * 1024;
            f16x8 bm0 = *(const f16x8*)(Bm + ko);
            f16x8 bm1 = *(const f16x8*)(Bm + 2048 + ko);
            f16x8 bnh = *(const f16x8*)(Bn + ko);
            f16x8 bnl = *(const f16x8*)(Bn + 2048 + ko);
            f16x8 ahn = *(const f16x8*)(A_ + fins * 2048 + ko);
            f16x8 aln = *(const f16x8*)(A_ + 16384 + fins * 2048 + ko);
            #pragma unroll
            for (int fi = 0; fi < 4; ++fi) {
                f16x8 ah = *(const f16x8*)(A_ + fi * 2048 + ko);
                accm[fi][0] = __builtin_amdgcn_mfma_f32_16x16x32_f16(ah, bm0, accm[fi][0], 0, 0, 0);
                accm[fi][1] = __builtin_amdgcn_mfma_f32_16x16x32_f16(ah, bm1, accm[fi][1], 0, 0, 0);
            }
            accn = __builtin_amdgcn_mfma_f32_16x16x32_f16(ahn, bnh, accn, 0, 0, 0);
            accn = __builtin_amdgcn_mfma_f32_16x16x32_f16(ahn, bnl, accn, 0, 0, 0);
            accn = __builtin_amdgcn_mfma_f32_16x16x32_f16(aln, bnh, accn, 0, 0, 0);
        }
        __builtin_amdgcn_sched_barrier(0);
        __builtin_amdgcn_s_barrier();
    }

    // D layout (m89-verified): col = lane&15, row = (lane>>4)*4 + reg
    const int row0 = mt * 128 + wr * 64 + ((lane >> 4) << 2);
    const int col0 = nbt * 128 + wc * 32 + (lane & 15);
    #pragma unroll
    for (int fi = 0; fi < 4; ++fi)
        #pragma unroll
        for (int fj = 0; fj < 2; ++fj)
            #pragma unroll
            for (int j = 0; j < 4; ++j) {
                size_t idx = (size_t)(row0 + fi * 16 + j) * BSD + col0 + fj * 16;
                X[idx] = accm[fi][fj][j] + X[idx];   // identity term (gated input, fp32)
            }
    const int nr0 = mt * 128 + wid * 16 + ((lane >> 4) << 2);
    const int nc  = nbt * 16 + (lane & 15);
    #pragma unroll
    for (int j = 0; j < 4; ++j) {
        size_t nidx = (size_t)(nr0 + j) * 64 + nc;
        nsout[nidx] = accn[j] + mg[nidx];            // identity term (gated mean, fp32)
    }
}

// ================================================================= readout
__global__ __launch_bounds__(256) void readout_kernel(const float* __restrict__ X3,
                                                      const float* __restrict__ W,
                                                      float* __restrict__ out) {
    __shared__ float Wt[64][65];
    __shared__ float xr[512];
    const int n = blockIdx.x;
    const int t = threadIdx.x;
    for (int e = t; e < 4096; e += 256) {
        int s = e >> 6, sp = e & 63;
        Wt[sp][s] = W[e];
    }
    xr[t]       = X3[(size_t)n * BSD + t];
    xr[t + 256] = X3[(size_t)n * BSD + 256 + t];
    __syncthreads();
    const int b1 = t >> 6;
    const int s  = t & 63;
    float acc0 = 0.0f, acc1 = 0.0f;
    #pragma unroll
    for (int sp = 0; sp < 64; ++sp) {
        float w = Wt[sp][s];
        acc0 += w * xr[b1 * 64 + sp];
        acc1 += w * xr[(b1 + 4) * 64 + sp];
    }
    out[((size_t)b1 * NN + n) * SS + s]       = acc0;
    out[((size_t)(b1 + 4) * NN + n) * SS + s] = acc1;
}

// ================================== temporal avg + enc + dec + top-k collapse
__global__ void nsfinal_kernel(const float* __restrict__ ns0,
                               const float* __restrict__ enc_w, const float* __restrict__ enc_b,
                               const float* __restrict__ dec_w, const float* __restrict__ dec_b,
                               float* __restrict__ out_ns) {
    int gtid = blockIdx.x * 256 + threadIdx.x;
    int lane = gtid & 63;
    const float r = 0.9f;
    const float wsum = 1.0f + r + r * r;
    float tns = (ns0[gtid] * (r * r) + ns0[NS + gtid] * r + ns0[2 * NS + gtid]) / wsum;
    float v = dec_b[lane];
    #pragma unroll
    for (int c = 0; c < 16; ++c) {
        float p = tns * enc_w[c * 64 + lane];
        #pragma unroll
        for (int off = 32; off; off >>= 1) p += __shfl_xor(p, off, 64);
        float h = fmaxf(p + enc_b[c], 0.0f);
        v += h * dec_w[lane * 16 + c];
    }
    float av = fabsf(v);
    int cnt = 0;
    for (int j = 0; j < 64; ++j) {
        float o = __shfl(av, j, 64);
        cnt += (o > av) ? 1 : 0;
    }
    out_ns[gtid] = (cnt < 8) ? v : 0.0f;
}

// ================================================================= launch
extern "C" void kernel_launch(void* const* d_in, const int* in_sizes, int n_in,
                              void* d_out, int out_size, void* d_ws, size_t ws_size,
                              hipStream_t stream) {
    const float* x      = (const float*)d_in[0];
    const float* ent    = (const float*)d_in[1];
    const float* mixing = (const float*)d_in[2];
    const float* r_w    = (const float*)d_in[3];
    const float* enc_w  = (const float*)d_in[4];
    const float* enc_b  = (const float*)d_in[5];
    const float* dec_w  = (const float*)d_in[6];
    const float* dec_b  = (const float*)d_in[7];
    float* out = (float*)d_out;

    char*  Ab   = (char*)d_ws;                    // 256 MB  (D hi|lo tiles)
    char*  Bb   = Ab + 268435456ull;              // 8 MB    (B main f16 tiles)
    char*  Nb   = Bb + 8388608ull;                // 2 MB    (B ns split tiles)
    float* X    = (float*)(Nb + 2097152ull);      // 16 MB   (activation, in-place)
    float* mg32 = X + NBS;                        // 2 MB    (gated mean fp32)
    float* ns0  = mg32 + NS;                      // 6 MB    (3 layer means)
    float* gate = ns0 + 3 * (size_t)NS;           // 2 MB

    sigmoid_gate_kernel<<<NS / 256, 256, 0, stream>>>(ent, gate);
    convA_kernel<<<dim3(128, 64), 256, 0, stream>>>(mixing, Ab);
    prep0_kernel<<<128, 256, 0, stream>>>(x, gate, X, Bb, Nb, mg32);

    for (int l = 0; l < 3; ++l) {
        gemm_f16_kernel<<<256, 512, 0, stream>>>(Ab, Bb, Nb, X, mg32, ns0 + (size_t)l * NS);
        if (l < 2)
            gateconv_kernel<<<128, 256, 0, stream>>>(X, gate, ns0 + (size_t)l * NS, Bb, Nb, mg32);
    }

    readout_kernel<<<NN, 256, 0, stream>>>(X, r_w, out);
    nsfinal_kernel<<<2048, 256, 0, stream>>>(ns0, enc_w, enc_b, dec_w, dec_b, out + NBS);
}